// Round 1
// baseline (6726.719 us; speedup 1.0000x reference)
//
#include <hip/hip_runtime.h>
#include <cstdint>
#include <cstddef>

// DiagonalLSTM: B=32, C=64, H=64, W=64, hid=64, 4h=256, NW=127
// K0: repack w_s2s/w_c2c (o,k,2) -> Wg[o][128] = [Ws0_row | Ws1_row], Wc likewise
// K1: i2s_v[b][r][w][o] (bf16, incl b_i2s) = conv1x1(inputs)
// K2: sequential diagonal scan, one workgroup per batch (full row-mixing per
//     step due to the flattened-axis gate split => per-batch sync domain)
// K3: out[b][o2][r][w] = w_up @ hh + b_up

#define NB 32
#define NC 64
#define NH 64
#define NWID 64
#define HID 64
#define NG 256
#define NSTEP 127

static __device__ __forceinline__ unsigned short f2bf(float f) {
    unsigned u = __builtin_bit_cast(unsigned, f);
    unsigned r = u + 0x7FFFu + ((u >> 16) & 1u);
    return (unsigned short)(r >> 16);
}
static __device__ __forceinline__ unsigned pack2(float a, float b) {
    return (unsigned)f2bf(a) | ((unsigned)f2bf(b) << 16);
}
static __device__ __forceinline__ float bf2f(unsigned short s) {
    return __builtin_bit_cast(float, ((unsigned)s) << 16);
}
static __device__ __forceinline__ float lo2f(unsigned u) {
    return __builtin_bit_cast(float, u << 16);
}
static __device__ __forceinline__ float hi2f(unsigned u) {
    return __builtin_bit_cast(float, u & 0xFFFF0000u);
}
static __device__ __forceinline__ float sigm(float x) {
    x = fminf(fmaxf(x, -30.f), 30.f);
    return 1.f / (1.f + __expf(-x));
}
static __device__ __forceinline__ float tanh_fast(float x) {
    x = fminf(fmaxf(x, -15.f), 15.f);
    float e = __expf(2.f * x);
    return (e - 1.f) / (e + 1.f);
}

// ---------------- K0: weight repack ----------------
__global__ __launch_bounds__(256) void repack_w(
    const float* __restrict__ w_s2s, const float* __restrict__ w_c2c,
    float* __restrict__ Wg, float* __restrict__ Wc) {
    int idx = blockIdx.x * 256 + threadIdx.x;
    if (idx < NG * 128) {
        int o = idx >> 7, kk = idx & 127, half = kk >> 6, k = kk & 63;
        Wg[idx] = w_s2s[(o * 64 + k) * 2 + half];
    }
    int j = idx - NG * 128;
    if (j >= 0 && j < HID * 128) {
        int o = j >> 7, kk = j & 127, half = kk >> 6, k = kk & 63;
        Wc[j] = w_c2c[(o * 64 + k) * 2 + half];
    }
}

// ---------------- K1: i2s (valid positions only, bf16 out, bias included) ----
// block 256 = 4 waves, one wg per (b,r). lane = w. wave wv handles o in
// [wv*64, wv*64+64). Inputs cached in 64 VGPRs; weights via wave-uniform
// scalar loads; LDS transpose so stores are o-contiguous (packed bf16 pairs).
__global__ __launch_bounds__(256) void i2s_kernel(
    const float* __restrict__ in, const float* __restrict__ w_i2s,
    const float* __restrict__ b_i2s, unsigned* __restrict__ i2s_u32) {
    const int bid = blockIdx.x;
    const int b = bid >> 6, r = bid & 63;
    const int lane = threadIdx.x & 63;
    const int wv = threadIdx.x >> 6;
    const int wvu = __builtin_amdgcn_readfirstlane(wv);

    __shared__ float sT[4][64][17];

    float vIn[64];
    const float* inp = in + ((size_t)b * 64 * 64 * 64) + r * 64 + lane;
#pragma unroll
    for (int c = 0; c < 64; c++) vIn[c] = inp[(size_t)c * 4096];

    const size_t outbase = ((size_t)(b * 64 + r)) * 64 * 128; // uint units

    for (int ob = 0; ob < 4; ob++) {
        float acc[16];
#pragma unroll
        for (int i = 0; i < 16; i++) {
            const int o = wvu * 64 + ob * 16 + i;
            float a = b_i2s[o];
            const float* wr = w_i2s + o * 64;
#pragma unroll
            for (int c = 0; c < 64; c++) a += wr[c] * vIn[c];
            acc[i] = a;
        }
#pragma unroll
        for (int i = 0; i < 16; i++) sT[wv][lane][i] = acc[i];
        // wave-internal LDS ordering handled by compiler waitcnts
#pragma unroll
        for (int j = 0; j < 8; j++) {
            int wr2 = j * 8 + (lane >> 3), olp = lane & 7;
            float v0 = sT[wv][wr2][2 * olp];
            float v1 = sT[wv][wr2][2 * olp + 1];
            i2s_u32[outbase + (size_t)wr2 * 128 + wvu * 32 + ob * 8 + olp] =
                pack2(v0, v1);
        }
    }
}

// ---------------- K2: the scan ----------------
// grid = 32 (one wg per batch), block = 1024 (16 waves).
// Stage A (lane = pre-row p, wave wv owns gates o in [wv*16,wv*16+16) and c2c
// outputs [wv*4,wv*4+4)): pre[p][o] = i2s + b_s2s + Wg[o]·[h_sh|h], written to
// LDS as bf16. Stage B (thread owns state (p2, k0..k0+3)): gate scramble
// ig=pre[q], gg=pre[16+q], fg=pre[32+q], og=pre[48+q] at col 64*(p2&3)+k.
__global__ __launch_bounds__(1024) void scan_kernel(
    const unsigned short* __restrict__ i2s_bf, const float* __restrict__ Wg,
    const float* __restrict__ Wc, const float* __restrict__ b_i2s,
    const float* __restrict__ b_s2s, const float* __restrict__ b_c2c,
    float* __restrict__ hh_v) {
    const int b = blockIdx.x;
    const int tid = threadIdx.x;
    const int lane = tid & 63;
    const int wv = tid >> 6;
    const int wvu = __builtin_amdgcn_readfirstlane(wv);
    const int p2 = tid >> 4;
    const int g4 = (tid & 15) * 4;
    const int q = p2 >> 2, e = p2 & 3;

    // bf16 pairs stored as uint. strides (uints): sH/sC/sCC 33, sPre 129.
    __shared__ unsigned sH[65 * 33];   // row 0 = zero pad; row p+1 = h[p]
    __shared__ unsigned sC[65 * 33];
    __shared__ unsigned sPre[64 * 129];
    __shared__ unsigned sCC[64 * 33];

    for (int i = tid; i < 65 * 33; i += 1024) { sH[i] = 0; sC[i] = 0; }
    __syncthreads();

    const unsigned short* i2s_b = i2s_bf + ((size_t)b) * 64 * 64 * 256;
    float* hh_b = hh_v + ((size_t)b) * 64 * 64 * 64;

    for (int t = 0; t < NSTEP; t++) {
        // ---------- stage A: gates ----------
        float acc[16];
        {
            int w = t - lane;
            int wc = min(max(w, 0), 63);
            bool valid = (w >= 0) && (w < 64);
#pragma unroll
            for (int i = 0; i < 16; i++) {
                int o = wvu * 16 + i;
                float iv = bf2f(i2s_b[(size_t)(lane * 64 + wc) * 256 + o]);
                acc[i] = (valid ? iv : b_i2s[o]) + b_s2s[o];
            }
        }
#pragma unroll
        for (int half = 0; half < 2; half++) {
            int row = lane + half; // half0: h_shift (=h[p-1]), half1: h[p]
#pragma unroll
            for (int kb = 0; kb < 2; kb++) {
                float vh[32];
#pragma unroll
                for (int j = 0; j < 16; j++) {
                    unsigned u = sH[row * 33 + kb * 16 + j];
                    vh[2 * j] = lo2f(u);
                    vh[2 * j + 1] = hi2f(u);
                }
#pragma unroll
                for (int i = 0; i < 16; i++) {
                    const float* wr = Wg + (wvu * 16 + i) * 128 + half * 64 + kb * 32;
                    float a = acc[i];
#pragma unroll
                    for (int k = 0; k < 32; k++) a += wr[k] * vh[k];
                    acc[i] = a;
                }
            }
        }
#pragma unroll
        for (int i = 0; i < 8; i++)
            sPre[lane * 129 + wvu * 8 + i] = pack2(acc[2 * i], acc[2 * i + 1]);

        // ---------- stage A: c2c ----------
        float ac[4];
#pragma unroll
        for (int j = 0; j < 4; j++) ac[j] = b_c2c[wvu * 4 + j];
#pragma unroll
        for (int half = 0; half < 2; half++) {
            int row = lane + half;
#pragma unroll
            for (int kb = 0; kb < 2; kb++) {
                float vc[32];
#pragma unroll
                for (int j = 0; j < 16; j++) {
                    unsigned u = sC[row * 33 + kb * 16 + j];
                    vc[2 * j] = lo2f(u);
                    vc[2 * j + 1] = hi2f(u);
                }
#pragma unroll
                for (int j = 0; j < 4; j++) {
                    const float* wr = Wc + (wvu * 4 + j) * 128 + half * 64 + kb * 32;
                    float a = ac[j];
#pragma unroll
                    for (int k = 0; k < 32; k++) a += wr[k] * vc[k];
                    ac[j] = a;
                }
            }
        }
        sCC[lane * 33 + wvu * 2] = pack2(ac[0], ac[1]);
        sCC[lane * 33 + wvu * 2 + 1] = pack2(ac[2], ac[3]);

        __syncthreads();

        // ---------- stage B: scrambled LSTM update ----------
        float hn[4], cn[4];
#pragma unroll
        for (int i2 = 0; i2 < 2; i2++) {
            int colu = e * 32 + (g4 >> 1) + i2;
            unsigned uig = sPre[q * 129 + colu];
            unsigned ugg = sPre[(16 + q) * 129 + colu];
            unsigned ufg = sPre[(32 + q) * 129 + colu];
            unsigned uog = sPre[(48 + q) * 129 + colu];
            unsigned ucc = sCC[p2 * 33 + (g4 >> 1) + i2];
#pragma unroll
            for (int m = 0; m < 2; m++) {
                float pig = m ? hi2f(uig) : lo2f(uig);
                float pgg = m ? hi2f(ugg) : lo2f(ugg);
                float pfg = m ? hi2f(ufg) : lo2f(ufg);
                float pog = m ? hi2f(uog) : lo2f(uog);
                float cc = m ? hi2f(ucc) : lo2f(ucc);
                float c1 = sigm(pfg) * cc + sigm(pig) * sigm(pgg);
                float h1 = sigm(pog) * tanh_fast(c1);
                cn[i2 * 2 + m] = c1;
                hn[i2 * 2 + m] = h1;
            }
        }
        sH[(p2 + 1) * 33 + (g4 >> 1)] = pack2(hn[0], hn[1]);
        sH[(p2 + 1) * 33 + (g4 >> 1) + 1] = pack2(hn[2], hn[3]);
        sC[(p2 + 1) * 33 + (g4 >> 1)] = pack2(cn[0], cn[1]);
        sC[(p2 + 1) * 33 + (g4 >> 1) + 1] = pack2(cn[2], cn[3]);

        int w2 = t - p2;
        if (w2 >= 0 && w2 < 64) {
            float4 v = make_float4(hn[0], hn[1], hn[2], hn[3]);
            *(float4*)(hh_b + (size_t)(p2 * 64 + w2) * 64 + g4) = v;
        }
        __syncthreads();
    }
}

// ---------------- K3: up-projection ----------------
__global__ __launch_bounds__(256) void up_kernel(
    const float* __restrict__ hh_v, const float* __restrict__ w_up,
    const float* __restrict__ b_up, float* __restrict__ out) {
    const int bid = blockIdx.x;
    const int b = bid >> 6, r = bid & 63;
    const int lane = threadIdx.x & 63;
    const int wv = threadIdx.x >> 6;
    const int wvu = __builtin_amdgcn_readfirstlane(wv);

    float v[64];
    const float4* src =
        (const float4*)(hh_v + ((size_t)(b * 64 + r) * 64 + lane) * 64);
#pragma unroll
    for (int j = 0; j < 16; j++) {
        float4 x = src[j];
        v[4 * j] = x.x; v[4 * j + 1] = x.y; v[4 * j + 2] = x.z; v[4 * j + 3] = x.w;
    }
    for (int i = 0; i < 32; i++) {
        int o2 = wvu * 32 + i;
        float a = b_up[o2];
        const float* wr = w_up + o2 * 64;
#pragma unroll
        for (int k = 0; k < 64; k++) a += wr[k] * v[k];
        out[((size_t)(b * 128 + o2) * 64 + r) * 64 + lane] = a;
    }
}

extern "C" void kernel_launch(void* const* d_in, const int* in_sizes, int n_in,
                              void* d_out, int out_size, void* d_ws,
                              size_t ws_size, hipStream_t stream) {
    (void)in_sizes; (void)n_in; (void)out_size; (void)ws_size;
    const float* inputs = (const float*)d_in[0];
    const float* w_i2s = (const float*)d_in[1];
    const float* b_i2s = (const float*)d_in[2];
    const float* w_s2s = (const float*)d_in[3];
    const float* b_s2s = (const float*)d_in[4];
    const float* w_c2c = (const float*)d_in[5];
    const float* b_c2c = (const float*)d_in[6];
    const float* w_up = (const float*)d_in[7];
    const float* b_up = (const float*)d_in[8];
    float* out = (float*)d_out;
    char* ws = (char*)d_ws;

    // workspace layout (bytes):
    // [0, 67108864)            i2s bf16  (32*64*64*256 u16)
    // [67108864, 100663296)    hh_v fp32 (32*64*64*64)
    // [100663296, 100794368)   Wg fp32 (256*128)
    // [100794368, 100827136)   Wc fp32 (64*128)
    unsigned short* i2s_bf = (unsigned short*)ws;
    float* hh_v = (float*)(ws + 67108864);
    float* Wg = (float*)(ws + 100663296);
    float* Wc = (float*)(ws + 100794368);

    hipLaunchKernelGGL(repack_w, dim3(160), dim3(256), 0, stream, w_s2s, w_c2c,
                       Wg, Wc);
    hipLaunchKernelGGL(i2s_kernel, dim3(2048), dim3(256), 0, stream, inputs,
                       w_i2s, b_i2s, (unsigned*)i2s_bf);
    hipLaunchKernelGGL(scan_kernel, dim3(32), dim3(1024), 0, stream, i2s_bf,
                       Wg, Wc, b_i2s, b_s2s, b_c2c, hh_v);
    hipLaunchKernelGGL(up_kernel, dim3(2048), dim3(256), 0, stream, hh_v, w_up,
                       b_up, out);
}

// Round 2
// 1316.533 us; speedup vs baseline: 5.1094x; 5.1094x over previous
//
#include <hip/hip_runtime.h>
#include <cstdint>
#include <cstddef>

// DiagonalLSTM B=32,C=64,H=64,W=64,h=64,4h=256,NW=127 — MFMA scan version.
// K0: repack w_s2s/w_c2c -> Wg[256][128], Wc[64][128] fp32
// K1: i2sP[b][p][w][o'] bf16, o' = (o&15)*16 + (o>>4), value = conv + b_i2s + b_s2s
// K2: scan, 1 block/batch, 8 waves, gates+c2c via mfma_f32_16x16x32_bf16,
//     weights VGPR-resident, i2s staged via global_load_lds into LDS slab
//     aliased with the pre-activation buffer.
// K3: up-projection (unchanged).

typedef unsigned int u32;
typedef unsigned short u16;
typedef __bf16 bf16x8 __attribute__((ext_vector_type(8)));
typedef float f32x4 __attribute__((ext_vector_type(4)));

#define NSTEP 127

static __device__ __forceinline__ u16 f2bf(float f) {
    u32 u = __builtin_bit_cast(u32, f);
    u32 r = u + 0x7FFFu + ((u >> 16) & 1u);
    return (u16)(r >> 16);
}
static __device__ __forceinline__ u32 pack2(float a, float b) {
    return (u32)f2bf(a) | ((u32)f2bf(b) << 16);
}
static __device__ __forceinline__ float lo2f(u32 u) {
    return __builtin_bit_cast(float, u << 16);
}
static __device__ __forceinline__ float hi2f(u32 u) {
    return __builtin_bit_cast(float, u & 0xFFFF0000u);
}
static __device__ __forceinline__ float bf2f(u16 s) {
    return __builtin_bit_cast(float, ((u32)s) << 16);
}
static __device__ __forceinline__ float sigm(float x) {
    x = fminf(fmaxf(x, -30.f), 30.f);
    return 1.f / (1.f + __expf(-x));
}
static __device__ __forceinline__ float tanh_fast(float x) {
    x = fminf(fmaxf(x, -15.f), 15.f);
    float e = __expf(2.f * x);
    return (e - 1.f) / (e + 1.f);
}
static __device__ __forceinline__ float bfel(uint4 v, int j) {
    u32 w = ((const u32*)&v)[j >> 1];
    return (j & 1) ? hi2f(w) : lo2f(w);
}

// ---------------- K0: weight repack ----------------
__global__ __launch_bounds__(256) void repack_w(
    const float* __restrict__ w_s2s, const float* __restrict__ w_c2c,
    float* __restrict__ Wg, float* __restrict__ Wc) {
    int idx = blockIdx.x * 256 + threadIdx.x;
    if (idx < 256 * 128) {
        int o = idx >> 7, kk = idx & 127, half = kk >> 6, k = kk & 63;
        Wg[idx] = w_s2s[(o * 64 + k) * 2 + half];
    }
    int j = idx - 256 * 128;
    if (j >= 0 && j < 64 * 128) {
        int o = j >> 7, kk = j & 127, half = kk >> 6, k = kk & 63;
        Wc[j] = w_c2c[(o * 64 + k) * 2 + half];
    }
}

// ---------------- K1: i2s, permuted-o layout, biases folded ----------------
// out u32 slab per (b,r): [w 64][o'-pair 128]; o' = (o&15)*16 + (o>>4)
__global__ __launch_bounds__(256) void i2s_kernel(
    const float* __restrict__ in, const float* __restrict__ w_i2s,
    const float* __restrict__ bi, const float* __restrict__ bs,
    u32* __restrict__ out_u32) {
    const int bid = blockIdx.x;
    const int b = bid >> 6, r = bid & 63;
    const int lane = threadIdx.x & 63;
    const int wv = threadIdx.x >> 6;
    const int wvu = __builtin_amdgcn_readfirstlane(wv);

    __shared__ __align__(16) u32 sT[4 * 64 * 33];

    float vIn[64];
    const float* inp = in + ((size_t)b * 262144) + r * 64 + lane;
#pragma unroll
    for (int c = 0; c < 64; c++) vIn[c] = inp[(size_t)c * 4096];

    for (int ob = 0; ob < 4; ob++) {
        float acc[16];
#pragma unroll
        for (int i = 0; i < 16; i++) {
            const int o = wvu * 64 + ob * 16 + i;
            float a = bi[o] + bs[o];
            const float* wr = w_i2s + o * 64;
#pragma unroll
            for (int c = 0; c < 64; c++) a += wr[c] * vIn[c];
            acc[i] = a;
        }
        // u32 [wvu*64+lane][i*2 + (ob>>1)], half (ob&1)
#pragma unroll
        for (int i = 0; i < 16; i++) {
            ((u16*)sT)[((wvu * 64 + lane) * 33 + i * 2 + (ob >> 1)) * 2 + (ob & 1)] =
                f2bf(acc[i]);
        }
    }
    __syncthreads();
    const size_t base = (size_t)(b * 64 + r) * 8192;  // u32 units
#pragma unroll
    for (int loop = 0; loop < 32; loop++) {
        int idx = loop * 256 + threadIdx.x;
        int w = idx >> 7, q7 = idx & 127;
        int i = q7 >> 3, ws = (q7 >> 1) & 3, c = q7 & 1;
        out_u32[base + idx] = sT[(ws * 64 + w) * 33 + i * 2 + c];
    }
}

// ---------------- K2: MFMA scan ----------------
// 32 blocks x 512 threads (8 waves). Wave w: mt=w&3, ng=w>>2.
// Gate tiles: (mt, n=8*ng+nn, nn 0..7). c2c tiles: (mt, n2=2*ng+j2, j2 0..1).
__global__ __launch_bounds__(512, 2) void scan_kernel(
    const u32* __restrict__ i2sP, const float* __restrict__ Wg,
    const float* __restrict__ Wc, const float* __restrict__ b_i2s,
    const float* __restrict__ b_s2s, const float* __restrict__ b_c2c,
    float* __restrict__ hh_v) {
    const int b = blockIdx.x;
    const int tid = threadIdx.x;
    const int lane = tid & 63;
    const int wv = __builtin_amdgcn_readfirstlane(tid >> 6);
    const int mt = wv & 3, ng = wv >> 2;
    const int m15 = lane & 15, g4 = lane >> 4;

    // LDS: sPX = union of sI2S[64][256]bf16 (flat rows 512B, 16B-chunk swizzle
    // by rho=(row>>2)&7 applied on the GLOBAL side) and sPreT[256 o][64 p]bf16
    // (group-swizzled g^(o&7)). sH/sC rows 128B swizzled. sCC swizzled u^(k&30).
    __shared__ __align__(16) u32 sPX[8192];
    __shared__ __align__(16) u32 sH[65 * 32];
    __shared__ __align__(16) u32 sC[65 * 32];
    __shared__ __align__(16) u32 sCC[64 * 32];

    for (int i = tid; i < 65 * 32; i += 512) { sH[i] = 0; sC[i] = 0; }

    // ---- preload weight B-fragments (bf16) ----
    bf16x8 BW[8][4];
    float Cb[8];  // invalid-position constant: b_i2s[o]+b_s2s[o]
#pragma unroll
    for (int nn = 0; nn < 8; nn++) {
        int o = 16 * (8 * ng + nn) + m15;
        Cb[nn] = b_i2s[o] + b_s2s[o];
#pragma unroll
        for (int kt = 0; kt < 4; kt++) {
            const float* p = Wg + o * 128 + kt * 32 + g4 * 8;
            bf16x8 f;
#pragma unroll
            for (int j = 0; j < 8; j++) f[j] = (__bf16)p[j];
            BW[nn][kt] = f;
        }
    }
    bf16x8 BC[2][4];
#pragma unroll
    for (int j2 = 0; j2 < 2; j2++) {
        int o2 = 16 * (2 * ng + j2) + m15;
#pragma unroll
        for (int kt = 0; kt < 4; kt++) {
            const float* p = Wc + o2 * 128 + kt * 32 + g4 * 8;
            bf16x8 f;
#pragma unroll
            for (int j = 0; j < 8; j++) f[j] = (__bf16)p[j];
            BC[j2][kt] = f;
        }
    }

    // stage-B per-thread constants
    const int kB = tid & 63, eB = (tid >> 6) & 3, halfB = tid >> 8;
    const float bcc = b_c2c[kB];
    const int oB = 64 * eB + kB;

    const u32* i2s_b = i2sP + (size_t)b * 524288;  // 64*64*128 u32 per batch
    float* hh_b = hh_v + (size_t)b * 262144;

    __syncthreads();

    for (int t = 0; t < NSTEP; t++) {
        // ---- stage i2s slab for this step: wave stages its own 16 rows ----
#pragma unroll
        for (int i = 0; i < 8; i++) {
            int p = 16 * mt + 2 * i + (lane >> 5);
            int w = min(max(t - p, 0), 63);
            int cg = (lane & 31) ^ ((4 * mt + (i >> 1)) & 7);
            const u32* g = i2s_b + (size_t)(p * 64 + w) * 128 + cg * 4;
            u32* l = sPX + (16 * mt + 2 * i) * 128;
            __builtin_amdgcn_global_load_lds(
                (const __attribute__((address_space(1))) u32*)g,
                (__attribute__((address_space(3))) u32*)l, 16, 0, 0);
        }

        // ---- MFMA phase ----
        f32x4 accG[8] = {};
        f32x4 accC2[2] = {};
        bf16x8 Ag[4], Ac[4];
#pragma unroll
        for (int kt = 0; kt < 4; kt++) {
            int row = 16 * mt + m15 + (kt >> 1);  // kt<2: h_shift(p), kt>=2: h(p)
            int g = (kt & 1) * 4 + g4;
            u32 idx = row * 32 + ((g ^ (row & 7)) << 2);
            Ag[kt] = __builtin_bit_cast(bf16x8, *(const uint4*)(sH + idx));
            Ac[kt] = __builtin_bit_cast(bf16x8, *(const uint4*)(sC + idx));
        }
#pragma unroll
        for (int nn = 0; nn < 8; nn++)
#pragma unroll
            for (int kt = 0; kt < 4; kt++)
                accG[nn] = __builtin_amdgcn_mfma_f32_16x16x32_bf16(
                    Ag[kt], BW[nn][kt], accG[nn], 0, 0, 0);
#pragma unroll
        for (int j2 = 0; j2 < 2; j2++)
#pragma unroll
            for (int kt = 0; kt < 4; kt++)
                accC2[j2] = __builtin_amdgcn_mfma_f32_16x16x32_bf16(
                    Ac[kt], BC[j2][kt], accC2[j2], 0, 0, 0);

        // ---- consume i2s slab (per-wave wait: rows were self-staged) ----
        __builtin_amdgcn_s_waitcnt(0x0F70);  // vmcnt(0)
        __builtin_amdgcn_sched_barrier(0);
#pragma unroll
        for (int r = 0; r < 4; r++) {
            int row = 16 * mt + 4 * g4 + r;
            bool valid = (u32)(t - row) < 64u;
            u32 idx = row * 128 + (((2 * m15 + ng) ^ ((4 * mt + g4) & 7)) << 2);
            uint4 v = *(const uint4*)(sPX + idx);
#pragma unroll
            for (int nn = 0; nn < 8; nn++) {
                float iv = bfel(v, nn);
                accG[nn][r] += valid ? iv : Cb[nn];
            }
        }
        __syncthreads();  // A2: all i2s reads done before sPreT overwrites slab

        // ---- write pre (transposed, swizzled) + c2c ----
        {
            int u0 = 8 * mt + 2 * g4;
            int gq = u0 >> 2, lo2 = u0 & 3;
#pragma unroll
            for (int nn = 0; nn < 8; nn++) {
                int o = 16 * (8 * ng + nn) + m15;
                uint2 wv2;
                wv2.x = pack2(accG[nn][0], accG[nn][1]);
                wv2.y = pack2(accG[nn][2], accG[nn][3]);
                *(uint2*)(sPX + o * 32 + ((gq ^ (o & 7)) << 2) + lo2) = wv2;
            }
#pragma unroll
            for (int j2 = 0; j2 < 2; j2++) {
                int kcol = 16 * (2 * ng + j2) + m15;
                uint2 wv2;
                wv2.x = pack2(accC2[j2][0], accC2[j2][1]);
                wv2.y = pack2(accC2[j2][2], accC2[j2][3]);
                *(uint2*)(sCC + kcol * 32 + (u0 ^ (kcol & 30))) = wv2;
            }
        }
        __syncthreads();  // B: pre/cc visible

        // ---- stage B: scrambled LSTM update ----
        {
            uint4 G[4];
#pragma unroll
            for (int g = 0; g < 4; g++) {
                int gsw = 2 * g + halfB;
                G[g] = *(const uint4*)(sPX + oB * 32 + ((gsw ^ (oB & 7)) << 2));
            }
#pragma unroll
            for (int qq = 0; qq < 8; qq++) {
                int q = 8 * halfB + qq;
                int p2 = 4 * q + eB;
                int u = p2 >> 1;
                u32 cw = sCC[kB * 32 + (u ^ (kB & 30))];
                float cc = ((p2 & 1) ? hi2f(cw) : lo2f(cw)) + bcc;
                float pig = bfel(G[0], qq), pgg = bfel(G[1], qq);
                float pfg = bfel(G[2], qq), pog = bfel(G[3], qq);
                float c1 = sigm(pfg) * cc + sigm(pig) * sigm(pgg);
                float h1 = sigm(pog) * tanh_fast(c1);
                int row = p2 + 1;
                int pu = (((kB >> 3) ^ (row & 7)) << 2) + ((kB >> 1) & 3);
                ((u16*)sH)[(row * 32 + pu) * 2 + (kB & 1)] = f2bf(h1);
                ((u16*)sC)[(row * 32 + pu) * 2 + (kB & 1)] = f2bf(c1);
                int w2 = t - p2;
                if ((u32)w2 < 64u)
                    hh_b[(size_t)(p2 * 64 + w2) * 64 + kB] = h1;
            }
        }
        __syncthreads();  // C: sH/sC ready for t+1; slab free for next DMA
    }
}

// ---------------- K3: up-projection ----------------
__global__ __launch_bounds__(256) void up_kernel(
    const float* __restrict__ hh_v, const float* __restrict__ w_up,
    const float* __restrict__ b_up, float* __restrict__ out) {
    const int bid = blockIdx.x;
    const int b = bid >> 6, r = bid & 63;
    const int lane = threadIdx.x & 63;
    const int wv = threadIdx.x >> 6;
    const int wvu = __builtin_amdgcn_readfirstlane(wv);

    float v[64];
    const float4* src =
        (const float4*)(hh_v + ((size_t)(b * 64 + r) * 64 + lane) * 64);
#pragma unroll
    for (int j = 0; j < 16; j++) {
        float4 x = src[j];
        v[4 * j] = x.x; v[4 * j + 1] = x.y; v[4 * j + 2] = x.z; v[4 * j + 3] = x.w;
    }
    for (int i = 0; i < 32; i++) {
        int o2 = wvu * 32 + i;
        float a = b_up[o2];
        const float* wr = w_up + o2 * 64;
#pragma unroll
        for (int k = 0; k < 64; k++) a += wr[k] * v[k];
        out[((size_t)(b * 128 + o2) * 64 + r) * 64 + lane] = a;
    }
}

extern "C" void kernel_launch(void* const* d_in, const int* in_sizes, int n_in,
                              void* d_out, int out_size, void* d_ws,
                              size_t ws_size, hipStream_t stream) {
    (void)in_sizes; (void)n_in; (void)out_size; (void)ws_size;
    const float* inputs = (const float*)d_in[0];
    const float* w_i2s = (const float*)d_in[1];
    const float* b_i2s = (const float*)d_in[2];
    const float* w_s2s = (const float*)d_in[3];
    const float* b_s2s = (const float*)d_in[4];
    const float* w_c2c = (const float*)d_in[5];
    const float* b_c2c = (const float*)d_in[6];
    const float* w_up = (const float*)d_in[7];
    const float* b_up = (const float*)d_in[8];
    float* out = (float*)d_out;
    char* ws = (char*)d_ws;

    // workspace layout (bytes) — identical footprint to round 1 (known to fit):
    // [0, 67108864)            i2sP bf16 (32*64*64*256 u16, permuted-o)
    // [67108864, 100663296)    hh_v fp32 (32*64*64*64)
    // [100663296, 100794368)   Wg fp32 (256*128)
    // [100794368, 100827136)   Wc fp32 (64*128)
    u32* i2sP = (u32*)ws;
    float* hh_v = (float*)(ws + 67108864);
    float* Wg = (float*)(ws + 100663296);
    float* Wc = (float*)(ws + 100794368);

    hipLaunchKernelGGL(repack_w, dim3(160), dim3(256), 0, stream, w_s2s, w_c2c,
                       Wg, Wc);
    hipLaunchKernelGGL(i2s_kernel, dim3(2048), dim3(256), 0, stream, inputs,
                       w_i2s, b_i2s, b_s2s, i2sP);
    hipLaunchKernelGGL(scan_kernel, dim3(32), dim3(512), 0, stream, i2sP, Wg,
                       Wc, b_i2s, b_s2s, b_c2c, hh_v);
    hipLaunchKernelGGL(up_kernel, dim3(2048), dim3(256), 0, stream, hh_v, w_up,
                       b_up, out);
}

// Round 3
// 661.139 us; speedup vs baseline: 10.1744x; 1.9913x over previous
//
#include <hip/hip_runtime.h>
#include <cstdint>
#include <cstddef>

// DiagonalLSTM B=32,C=64,H=64,W=64,h=64,4h=256,NW=127.
// Scan v3: gate-scramble absorbed into MFMA A-row permutation
//   P(m)=16*(m&3)+4*mt+(m>>2)  =>  lane (g4,m15), tile (mt,nb): acc regs r=0..3
//   are the 4 gates (ig,gg,fg,og) of state p2=16mt+4g4+nq, k=16nb+m15.
// Gates stay in fp32 registers; only h/c (double-buffered, swizzled) and a
// 1-bf16/state c2c exchange go through LDS. 2 barriers/step.
// K1 emits i2s with column permutation o'' = (o&15)*16 + (o>>6)*4 + ((o>>4)&3)
// so each lane's 4 gate i2s values are one 8B load.

typedef unsigned int u32;
typedef unsigned short u16;
typedef __bf16 bf16x8 __attribute__((ext_vector_type(8)));
typedef float f32x4 __attribute__((ext_vector_type(4)));

#define NSTEP 127
#define MFMA(a, b, c) __builtin_amdgcn_mfma_f32_16x16x32_bf16(a, b, c, 0, 0, 0)

static __device__ __forceinline__ u16 f2bf(float f) {
    u32 u = __builtin_bit_cast(u32, f);
    u32 r = u + 0x7FFFu + ((u >> 16) & 1u);
    return (u16)(r >> 16);
}
static __device__ __forceinline__ u32 pack2(float a, float b) {
    return (u32)f2bf(a) | ((u32)f2bf(b) << 16);
}
static __device__ __forceinline__ float lo2f(u32 u) {
    return __builtin_bit_cast(float, u << 16);
}
static __device__ __forceinline__ float hi2f(u32 u) {
    return __builtin_bit_cast(float, u & 0xFFFF0000u);
}
static __device__ __forceinline__ float sigm(float x) {
    return __builtin_amdgcn_rcpf(1.f + __expf(-x));
}
static __device__ __forceinline__ float tanh_fast(float x) {
    float e = __expf(2.f * x);
    return 1.f - 2.f * __builtin_amdgcn_rcpf(e + 1.f);
}

// ---------------- K0: weight repack ----------------
__global__ __launch_bounds__(256) void repack_w(
    const float* __restrict__ w_s2s, const float* __restrict__ w_c2c,
    float* __restrict__ Wg, float* __restrict__ Wc) {
    int idx = blockIdx.x * 256 + threadIdx.x;
    if (idx < 256 * 128) {
        int o = idx >> 7, kk = idx & 127, half = kk >> 6, k = kk & 63;
        Wg[idx] = w_s2s[(o * 64 + k) * 2 + half];
    }
    int j = idx - 256 * 128;
    if (j >= 0 && j < 64 * 128) {
        int o = j >> 7, kk = j & 127, half = kk >> 6, k = kk & 63;
        Wc[j] = w_c2c[(o * 64 + k) * 2 + half];
    }
}

// ---------------- K1: i2s conv, biases folded, o''-permuted ----------------
// i2sP flat u16: ((b*64+p)*64 + w)*256 + o'' ; o'' = (o&15)*16+(o>>6)*4+((o>>4)&3)
__global__ __launch_bounds__(256) void i2s_kernel(
    const float* __restrict__ in, const float* __restrict__ w_i2s,
    const float* __restrict__ bi, const float* __restrict__ bs,
    u32* __restrict__ out_u32) {
    const int bid = blockIdx.x;
    const int b = bid >> 6, r = bid & 63;
    const int lane = threadIdx.x & 63;
    const int wv = threadIdx.x >> 6;
    const int wvu = __builtin_amdgcn_readfirstlane(wv);

    __shared__ __align__(16) u32 sT[64 * 129];  // u16 [w 64][o'' 256], stride 258

    float vIn[64];
    const float* inp = in + ((size_t)b * 262144) + r * 64 + lane;
#pragma unroll
    for (int c = 0; c < 64; c++) vIn[c] = inp[(size_t)c * 4096];

    for (int ob = 0; ob < 4; ob++) {
        float acc[16];
#pragma unroll
        for (int i = 0; i < 16; i++) {
            const int o = wvu * 64 + ob * 16 + i;
            float a = bi[o] + bs[o];
            const float* wr = w_i2s + o * 64;
#pragma unroll
            for (int c = 0; c < 64; c++) a += wr[c] * vIn[c];
            acc[i] = a;
        }
#pragma unroll
        for (int i = 0; i < 16; i++)
            ((u16*)sT)[lane * 258 + i * 16 + wvu * 4 + ob] = f2bf(acc[i]);
    }
    __syncthreads();
    const size_t base = (size_t)(b * 64 + r) * 8192;  // u32 units
#pragma unroll
    for (int loop = 0; loop < 32; loop++) {
        int idx = loop * 256 + threadIdx.x;
        int w = idx >> 7, cu = idx & 127;
        out_u32[base + idx] = sT[w * 129 + cu];
    }
}

// ---------------- K2: MFMA scan v3 ----------------
// 32 blocks x 512 threads (8 waves). wave wv: mh=wv>>2 (M-half), nq=wv&3
// (gate e-block / state low bits). c2c tiles: mtc=wv>>1, ktc0=(wv&1)*2.
__global__ __launch_bounds__(512, 2) void scan_kernel(
    const u16* __restrict__ i2sP, const float* __restrict__ Wg,
    const float* __restrict__ Wc, const float* __restrict__ b_i2s,
    const float* __restrict__ b_s2s, const float* __restrict__ b_c2c,
    float* __restrict__ hh_v) {
    const int b = blockIdx.x;
    const int tid = threadIdx.x;
    const int lane = tid & 63;
    const int wv = __builtin_amdgcn_readfirstlane(tid >> 6);
    const int mh = wv >> 2, nq = wv & 3;
    const int mtc = wv >> 1, ktc0 = (wv & 1) * 2;
    const int m15 = lane & 15, g4 = lane >> 4;

    // sH/sC: [parity 2][row 65][32 u32], rows are 128B, 16B-chunk XOR swizzle
    // chunk' = chunk ^ ((row ^ row>>3)&7). Row 0 = zero pad (h[-1]=c[-1]=0).
    __shared__ __align__(16) u32 sH[2 * 2080];
    __shared__ __align__(16) u32 sC[2 * 2080];
    // sCC u32 [rowpair 32][64], col rotated by 8*rowpair (bf16 pair = rows 2rp,2rp+1)
    __shared__ __align__(16) u32 sCC[32 * 64];

    for (int i = tid; i < 2 * 2080; i += 512) { sH[i] = 0; sC[i] = 0; }

    // ---- VGPR-resident weights ----
    bf16x8 BW[4][4];
    float Cb[4], bcc[4];
#pragma unroll
    for (int nb = 0; nb < 4; nb++) {
        int o = 64 * nq + 16 * nb + m15;
        Cb[nb] = b_i2s[o] + b_s2s[o];
        bcc[nb] = b_c2c[16 * nb + m15];
#pragma unroll
        for (int kt = 0; kt < 4; kt++) {
            const float* p = Wg + o * 128 + kt * 32 + g4 * 8;
            bf16x8 f;
#pragma unroll
            for (int j = 0; j < 8; j++) f[j] = (__bf16)p[j];
            BW[nb][kt] = f;
        }
    }
    bf16x8 BC[2][4];
#pragma unroll
    for (int i = 0; i < 2; i++) {
        int o2 = 16 * (ktc0 + i) + m15;
#pragma unroll
        for (int kt = 0; kt < 4; kt++) {
            const float* p = Wc + o2 * 128 + kt * 32 + g4 * 8;
            bf16x8 f;
#pragma unroll
            for (int j = 0; j < 8; j++) f[j] = (__bf16)p[j];
            BC[i][kt] = f;
        }
    }

    const u16* i2s_b = i2sP + (size_t)b * 1048576;  // 64*64*256 u16
    // per-state global store base: idx = p2*4032 + t*64 + k, k=16nb+m15
    float* hbase[2];
#pragma unroll
    for (int mi = 0; mi < 2; mi++) {
        int p2 = 16 * (2 * mh + mi) + 4 * g4 + nq;
        hbase[mi] = hh_v + (size_t)b * 262144 + p2 * 4032 + m15;
    }

    __syncthreads();

    for (int t = 0; t < NSTEP; t++) {
        const int par = t & 1;
        const u32* bH = sH + par * 2080;
        const u32* bC = sC + par * 2080;

        // ---- prefetch i2s: per (mi,r) one 8B load = 4 gate values ----
        uint2 IV[2][4];
#pragma unroll
        for (int mi = 0; mi < 2; mi++) {
            int mt = 2 * mh + mi;
#pragma unroll
            for (int r = 0; r < 4; r++) {
                int prerow = 16 * r + 4 * mt + g4;
                int w = min(max(t - prerow, 0), 63);
                size_t off = (size_t)(prerow * 64 + w) * 512 + 32 * m15 + 8 * nq;
                IV[mi][r] = *(const uint2*)((const char*)i2s_b + off);
            }
        }

        // ---- gate MFMAs (permuted A rows) ----
        f32x4 accG[2][4] = {};
#pragma unroll
        for (int mi = 0; mi < 2; mi++) {
            int mt = 2 * mh + mi;
            bf16x8 Ag[4];
#pragma unroll
            for (int kt = 0; kt < 4; kt++) {
                int row16 = 16 * (m15 & 3) + 4 * mt + (m15 >> 2);
                int srow = row16 + (kt >> 1);  // kt<2: h_shift, kt>=2: h
                u32 idx = srow * 32 +
                          (((((kt & 1) * 4) + g4) ^ ((srow ^ (srow >> 3)) & 7)) << 2);
                Ag[kt] = __builtin_bit_cast(bf16x8, *(const uint4*)(bH + idx));
            }
#pragma unroll
            for (int nb = 0; nb < 4; nb++)
#pragma unroll
                for (int kt = 0; kt < 4; kt++)
                    accG[mi][nb] = MFMA(Ag[kt], BW[nb][kt], accG[mi][nb]);
        }
        // ---- c2c MFMAs (contiguous A rows) ----
        f32x4 accC[2] = {};
        {
            bf16x8 Ac[4];
#pragma unroll
            for (int kt = 0; kt < 4; kt++) {
                int srow = 16 * mtc + m15 + (kt >> 1);
                u32 idx = srow * 32 +
                          (((((kt & 1) * 4) + g4) ^ ((srow ^ (srow >> 3)) & 7)) << 2);
                Ac[kt] = __builtin_bit_cast(bf16x8, *(const uint4*)(bC + idx));
            }
#pragma unroll
            for (int i = 0; i < 2; i++)
#pragma unroll
                for (int kt = 0; kt < 4; kt++)
                    accC[i] = MFMA(Ac[kt], BC[i][kt], accC[i]);
        }

        // ---- add i2s (valid) / bias constant (invalid) ----
#pragma unroll
        for (int mi = 0; mi < 2; mi++) {
            int mt = 2 * mh + mi;
#pragma unroll
            for (int r = 0; r < 4; r++) {
                int prerow = 16 * r + 4 * mt + g4;
                bool valid = (u32)(t - prerow) < 64u;
                u32 w0 = IV[mi][r].x, w1 = IV[mi][r].y;
                accG[mi][0][r] += valid ? lo2f(w0) : Cb[0];
                accG[mi][1][r] += valid ? hi2f(w0) : Cb[1];
                accG[mi][2][r] += valid ? lo2f(w1) : Cb[2];
                accG[mi][3][r] += valid ? hi2f(w1) : Cb[3];
            }
        }

        // ---- publish c2c (bf16 row-pairs, rotated cols) ----
#pragma unroll
        for (int i = 0; i < 2; i++) {
            int k = 16 * (ktc0 + i) + m15;
            int rp0 = 8 * mtc + 2 * g4;
            sCC[rp0 * 64 + ((k + 8 * rp0) & 63)] = pack2(accC[i][0], accC[i][1]);
            int rp1 = rp0 + 1;
            sCC[rp1 * 64 + ((k + 8 * rp1) & 63)] = pack2(accC[i][2], accC[i][3]);
        }
        __syncthreads();  // c2c visible

        // ---- stage B: LSTM update, gates all in registers ----
        const int wpar = (t + 1) & 1;
        u16* wH = (u16*)(sH + wpar * 2080);
        u16* wC = (u16*)(sC + wpar * 2080);
#pragma unroll
        for (int mi = 0; mi < 2; mi++) {
            int mt = 2 * mh + mi;
            int p2 = 16 * mt + 4 * g4 + nq;
            int rp = p2 >> 1;
            bool vst = (u32)(t - p2) < 64u;
            float* hp = hbase[mi];
            int row = p2 + 1;
            int swr = (row ^ (row >> 3)) & 7;
#pragma unroll
            for (int nb = 0; nb < 4; nb++) {
                int k = 16 * nb + m15;
                u32 cw = sCC[rp * 64 + ((k + 8 * rp) & 63)];
                float cc = ((p2 & 1) ? hi2f(cw) : lo2f(cw)) + bcc[nb];
                float ig = accG[mi][nb][0], gg = accG[mi][nb][1];
                float fg = accG[mi][nb][2], og = accG[mi][nb][3];
                float c1 = sigm(fg) * cc + sigm(ig) * sigm(gg);
                float h1 = sigm(og) * tanh_fast(c1);
                int hw = row * 64 + ((((k >> 3) ^ swr)) << 3) + (k & 7);
                wH[hw] = f2bf(h1);
                wC[hw] = f2bf(c1);
                if (vst) hp[nb * 16] = h1;
            }
        }
        hbase[0] += 64;
        hbase[1] += 64;
        __syncthreads();  // new h/c + sCC reuse safe for t+1
    }
}

// ---------------- K3: up-projection ----------------
__global__ __launch_bounds__(256) void up_kernel(
    const float* __restrict__ hh_v, const float* __restrict__ w_up,
    const float* __restrict__ b_up, float* __restrict__ out) {
    const int bid = blockIdx.x;
    const int b = bid >> 6, r = bid & 63;
    const int lane = threadIdx.x & 63;
    const int wv = threadIdx.x >> 6;
    const int wvu = __builtin_amdgcn_readfirstlane(wv);

    float v[64];
    const float4* src =
        (const float4*)(hh_v + ((size_t)(b * 64 + r) * 64 + lane) * 64);
#pragma unroll
    for (int j = 0; j < 16; j++) {
        float4 x = src[j];
        v[4 * j] = x.x; v[4 * j + 1] = x.y; v[4 * j + 2] = x.z; v[4 * j + 3] = x.w;
    }
    for (int i = 0; i < 32; i++) {
        int o2 = wvu * 32 + i;
        float a = b_up[o2];
        const float* wr = w_up + o2 * 64;
#pragma unroll
        for (int k = 0; k < 64; k++) a += wr[k] * v[k];
        out[((size_t)(b * 128 + o2) * 64 + r) * 64 + lane] = a;
    }
}

extern "C" void kernel_launch(void* const* d_in, const int* in_sizes, int n_in,
                              void* d_out, int out_size, void* d_ws,
                              size_t ws_size, hipStream_t stream) {
    (void)in_sizes; (void)n_in; (void)out_size; (void)ws_size;
    const float* inputs = (const float*)d_in[0];
    const float* w_i2s = (const float*)d_in[1];
    const float* b_i2s = (const float*)d_in[2];
    const float* w_s2s = (const float*)d_in[3];
    const float* b_s2s = (const float*)d_in[4];
    const float* w_c2c = (const float*)d_in[5];
    const float* b_c2c = (const float*)d_in[6];
    const float* w_up = (const float*)d_in[7];
    const float* b_up = (const float*)d_in[8];
    float* out = (float*)d_out;
    char* ws = (char*)d_ws;

    // workspace layout (bytes), same footprint as r2 (fits):
    // [0, 67108864)            i2sP bf16 (32*64*64*256 u16, o''-permuted)
    // [67108864, 100663296)    hh_v fp32 (32*64*64*64)
    // [100663296, 100794368)   Wg fp32 (256*128)
    // [100794368, 100827136)   Wc fp32 (64*128)
    u16* i2sP = (u16*)ws;
    float* hh_v = (float*)(ws + 67108864);
    float* Wg = (float*)(ws + 100663296);
    float* Wc = (float*)(ws + 100794368);

    hipLaunchKernelGGL(repack_w, dim3(160), dim3(256), 0, stream, w_s2s, w_c2c,
                       Wg, Wc);
    hipLaunchKernelGGL(i2s_kernel, dim3(2048), dim3(256), 0, stream, inputs,
                       w_i2s, b_i2s, b_s2s, (u32*)i2sP);
    hipLaunchKernelGGL(scan_kernel, dim3(32), dim3(512), 0, stream, i2sP, Wg,
                       Wc, b_i2s, b_s2s, b_c2c, hh_v);
    hipLaunchKernelGGL(up_kernel, dim3(2048), dim3(256), 0, stream, hh_v, w_up,
                       b_up, out);
}

// Round 4
// 555.385 us; speedup vs baseline: 12.1118x; 1.1904x over previous
//
#include <hip/hip_runtime.h>
#include <cstdint>
#include <cstddef>

// DiagonalLSTM B=32,C=64,H=64,W=64,h=64,4h=256,NW=127 — scan v4.
// v4 changes vs v3: bias-padded i2sP (no validity selects), -log2e folded into
// gate weights/i2s (sigmoid = rcp(1+exp2(y))), precomputed LDS byte addrs with
// power-of-2 parity XOR (8192), hh stored bf16, K3 up-projection on MFMA.

typedef unsigned int u32;
typedef unsigned short u16;
typedef __bf16 bf16x8 __attribute__((ext_vector_type(8)));
typedef float f32x4 __attribute__((ext_vector_type(4)));

#define NSTEP 127
#define MFMA(a, b, c) __builtin_amdgcn_mfma_f32_16x16x32_bf16(a, b, c, 0, 0, 0)
#define LOG2E 1.4426950408889634f
#define SCL (-1.4426950408889634f)
#define T2L 2.8853900817779268f
#define RHO(r) ((((r) ^ ((r) >> 3))) & 7)

static __device__ __forceinline__ u16 f2bf(float f) {
    u32 u = __builtin_bit_cast(u32, f);
    u32 r = u + 0x7FFFu + ((u >> 16) & 1u);
    return (u16)(r >> 16);
}
static __device__ __forceinline__ u32 pack2(float a, float b) {
    return (u32)f2bf(a) | ((u32)f2bf(b) << 16);
}
static __device__ __forceinline__ float lo2f(u32 u) {
    return __builtin_bit_cast(float, u << 16);
}
static __device__ __forceinline__ float hi2f(u32 u) {
    return __builtin_bit_cast(float, u & 0xFFFF0000u);
}
static __device__ __forceinline__ float sigm2(float y) {  // y pre-scaled by -log2e
    return __builtin_amdgcn_rcpf(1.f + __builtin_amdgcn_exp2f(y));
}
static __device__ __forceinline__ float tanh_fast(float x) {
    float r = __builtin_amdgcn_rcpf(1.f + __builtin_amdgcn_exp2f(x * T2L));
    return __builtin_fmaf(-2.f, r, 1.f);
}

// ---------------- K0: weight repack ----------------
// Wg[o][128] = -log2e * [Ws0_row | Ws1_row]; Wc[o][128] = [Wc0 | Wc1] (unscaled)
// biasRow u16[256] (o''-layout) = bf(-log2e*(bi+bs)); w_upB u16[128*64] = bf(w_up)
__global__ __launch_bounds__(256) void repack_w(
    const float* __restrict__ w_s2s, const float* __restrict__ w_c2c,
    const float* __restrict__ bi, const float* __restrict__ bs,
    const float* __restrict__ w_up, float* __restrict__ Wg,
    float* __restrict__ Wc, u16* __restrict__ biasRow,
    u16* __restrict__ w_upB) {
    int idx = blockIdx.x * 256 + threadIdx.x;
    if (idx < 32768) {
        int o = idx >> 7, kk = idx & 127, half = kk >> 6, k = kk & 63;
        Wg[idx] = SCL * w_s2s[(o * 64 + k) * 2 + half];
        return;
    }
    int j = idx - 32768;
    if (j < 8192) {
        int o = j >> 7, kk = j & 127, half = kk >> 6, k = kk & 63;
        Wc[j] = w_c2c[(o * 64 + k) * 2 + half];
        return;
    }
    j -= 8192;
    if (j < 256) {
        int m15 = j >> 4, nq = (j >> 2) & 3, nb = j & 3;
        int o = 64 * nq + 16 * nb + m15;
        biasRow[j] = f2bf(SCL * (bi[o] + bs[o]));
        return;
    }
    j -= 256;
    if (j < 8192) w_upB[j] = f2bf(w_up[j]);
}

// ---------------- K1: i2s conv, scaled by -log2e, o''-permuted, bias-padded --
// slot (b,p,w): ((b*64+p)*66 + (w+1)) * 512 bytes; w=-1 and w=64 slots = biasRow
__global__ __launch_bounds__(256) void i2s_kernel(
    const float* __restrict__ in, const float* __restrict__ w_i2s,
    const float* __restrict__ bi, const float* __restrict__ bs,
    const u32* __restrict__ biasU32, u32* __restrict__ out_u32) {
    const int bid = blockIdx.x;
    const int b = bid >> 6, r = bid & 63;
    const int lane = threadIdx.x & 63;
    const int wv = threadIdx.x >> 6;
    const int wvu = __builtin_amdgcn_readfirstlane(wv);

    __shared__ __align__(16) u32 sT[64 * 129];  // u16 [w 64][o'' 256], stride 258

    float vIn[64];
    const float* inp = in + ((size_t)b * 262144) + r * 64 + lane;
#pragma unroll
    for (int c = 0; c < 64; c++) vIn[c] = inp[(size_t)c * 4096];

    for (int ob = 0; ob < 4; ob++) {
        float acc[16];
#pragma unroll
        for (int i = 0; i < 16; i++) {
            const int o = wvu * 64 + ob * 16 + i;
            float a = bi[o] + bs[o];
            const float* wr = w_i2s + o * 64;
#pragma unroll
            for (int c = 0; c < 64; c++) a += wr[c] * vIn[c];
            acc[i] = a;
        }
#pragma unroll
        for (int i = 0; i < 16; i++)
            ((u16*)sT)[lane * 258 + i * 16 + wvu * 4 + ob] = f2bf(SCL * acc[i]);
    }
    __syncthreads();
    const size_t base = ((size_t)(b * 64 + r) * 66 + 1) * 128;  // u32 units
#pragma unroll
    for (int loop = 0; loop < 32; loop++) {
        int idx = loop * 256 + threadIdx.x;
        int w = idx >> 7, cu = idx & 127;
        out_u32[base + idx] = sT[w * 129 + cu];
    }
    if (threadIdx.x < 128) {
        u32 v = biasU32[threadIdx.x];
        out_u32[base - 128 + threadIdx.x] = v;       // w = -1 slot
        out_u32[base + 8192 + threadIdx.x] = v;      // w = 64 slot
    }
}

// ---------------- K2: MFMA scan v4 ----------------
// 32 blocks x 512 threads (8 waves). wave wv: mh=wv>>2, nq=wv&3 => mt=2mh+mi.
// c2c: mtc=wv>>1, ktc0=(wv&1)*2.
// LDS sM bytes: [0,8192) H par0 rows0..63x128B; [8192,16384) H par1;
// [16384,32768) C par0/par1; ZH0@32768 ZC0@32896 ZH1@40960 ZC1@41088 (zeros).
// All H/C addrs XOR 8192 per step. Row chunks (16B) swizzled by RHO(row).
__global__ __launch_bounds__(512, 2) void scan_kernel(
    const u16* __restrict__ i2sP, const float* __restrict__ Wg,
    const float* __restrict__ Wc, const float* __restrict__ b_c2c,
    u16* __restrict__ hh16) {
    const int b = blockIdx.x;
    const int tid = threadIdx.x;
    const int lane = tid & 63;
    const int wv = __builtin_amdgcn_readfirstlane(tid >> 6);
    const int mh = wv >> 2, nq = wv & 3;
    const int mtc = wv >> 1, ktc0 = (wv & 1) * 2;
    const int m15 = lane & 15, g4 = lane >> 4;

    __shared__ __align__(16) u32 sM[10304];   // 41216 B
    __shared__ __align__(16) u32 sCCm[2048];  // 8192 B
    char* smB = (char*)sM;
    char* ccB = (char*)sCCm;

    for (int i = tid; i < 10304; i += 512) sM[i] = 0;

    // ---- VGPR-resident weights ----
    bf16x8 BW[4][4];
    float bcc[4];
#pragma unroll
    for (int nb = 0; nb < 4; nb++) {
        int o = 64 * nq + 16 * nb + m15;
        bcc[nb] = b_c2c[16 * nb + m15];
#pragma unroll
        for (int kt = 0; kt < 4; kt++) {
            const float* p = Wg + o * 128 + kt * 32 + g4 * 8;
            bf16x8 f;
#pragma unroll
            for (int j = 0; j < 8; j++) f[j] = (__bf16)p[j];
            BW[nb][kt] = f;
        }
    }
    bf16x8 BC[2][4];
#pragma unroll
    for (int i = 0; i < 2; i++) {
        int o2 = 16 * (ktc0 + i) + m15;
#pragma unroll
        for (int kt = 0; kt < 4; kt++) {
            const float* p = Wc + o2 * 128 + kt * 32 + g4 * 8;
            bf16x8 f;
#pragma unroll
            for (int j = 0; j < 8; j++) f[j] = (__bf16)p[j];
            BC[i][kt] = f;
        }
    }

    // ---- precomputed addresses ----
    int aG[2][4], aC[4], wOff[2][4], ccR[2][4], ccP[4], bOffB[2][4];
#pragma unroll
    for (int mi = 0; mi < 2; mi++) {
        int mt = 2 * mh + mi;
#pragma unroll
        for (int kt = 0; kt < 4; kt++) {
            int P = 16 * (m15 & 3) + 4 * mt + (m15 >> 2);
            int phys = P + (kt >> 1) - 1;
            int chunk = (kt & 1) * 4 + g4;
            aG[mi][kt] = (phys < 0) ? (32768 + chunk * 16)
                                    : (phys * 128 + ((chunk ^ RHO(phys)) * 16));
        }
        int p2 = 16 * mt + 4 * g4 + nq;
#pragma unroll
        for (int nb = 0; nb < 4; nb++) {
            int k = 16 * nb + m15;
            wOff[mi][nb] =
                8192 + p2 * 128 + (((k >> 3) ^ RHO(p2)) * 16) + (k & 7) * 2;
            int rp = p2 >> 1;
            ccR[mi][nb] = (rp * 64 + ((k + 8 * rp) & 63)) * 4;
            int prerow = 16 * nb + 4 * mt + g4;  // nb doubles as gate idx r here
            bOffB[mi][nb] = (prerow * 66 + 1) * 512 + 32 * m15 + 8 * nq;
        }
    }
#pragma unroll
    for (int kt = 0; kt < 4; kt++) {
        int crow = 16 * mtc + m15;
        int phys = crow + (kt >> 1) - 1;
        int chunk = (kt & 1) * 4 + g4;
        aC[kt] = (phys < 0) ? (32896 + chunk * 16)
                            : (16384 + phys * 128 + ((chunk ^ RHO(phys)) * 16));
    }
#pragma unroll
    for (int i = 0; i < 2; i++) {
        int k = 16 * (ktc0 + i) + m15;
        int rp0 = 8 * mtc + 2 * g4, rp1 = rp0 + 1;
        ccP[2 * i] = (rp0 * 64 + ((k + 8 * rp0) & 63)) * 4;
        ccP[2 * i + 1] = (rp1 * 64 + ((k + 8 * rp1) & 63)) * 4;
    }

    const char* i2sB = (const char*)i2sP + (size_t)b * (64 * 66 * 512);
    u16* hp16[2];
    int p2s[2];
#pragma unroll
    for (int mi = 0; mi < 2; mi++) {
        int p2 = 16 * (2 * mh + mi) + 4 * g4 + nq;
        p2s[mi] = p2;
        hp16[mi] = hh16 + (size_t)b * 262144 + p2 * 4032 + m15;
    }

    __syncthreads();

    for (int t = 0; t < NSTEP; t++) {
        // ---- i2s prefetch: one 8B load = 4 gate values (bias-padded) ----
        uint2 IV[2][4];
#pragma unroll
        for (int mi = 0; mi < 2; mi++) {
            int mt = 2 * mh + mi;
#pragma unroll
            for (int r = 0; r < 4; r++) {
                int prerow = 16 * r + 4 * mt + g4;
                int w = min(max(t - prerow, -1), 64);
                IV[mi][r] =
                    *(const uint2*)(i2sB + (bOffB[mi][r] + (w << 9)));
            }
        }

        // ---- gate MFMAs (permuted A rows) ----
        f32x4 accG[2][4] = {};
#pragma unroll
        for (int mi = 0; mi < 2; mi++) {
            bf16x8 Ag[4];
#pragma unroll
            for (int kt = 0; kt < 4; kt++)
                Ag[kt] = __builtin_bit_cast(bf16x8,
                                            *(const uint4*)(smB + aG[mi][kt]));
#pragma unroll
            for (int nb = 0; nb < 4; nb++)
#pragma unroll
                for (int kt = 0; kt < 4; kt++)
                    accG[mi][nb] = MFMA(Ag[kt], BW[nb][kt], accG[mi][nb]);
        }
        // ---- c2c MFMAs ----
        f32x4 accC[2] = {};
        {
            bf16x8 Ac[4];
#pragma unroll
            for (int kt = 0; kt < 4; kt++)
                Ac[kt] =
                    __builtin_bit_cast(bf16x8, *(const uint4*)(smB + aC[kt]));
#pragma unroll
            for (int i = 0; i < 2; i++)
#pragma unroll
                for (int kt = 0; kt < 4; kt++)
                    accC[i] = MFMA(Ac[kt], BC[i][kt], accC[i]);
        }

        // ---- add i2s (bias-padded: unconditional) ----
#pragma unroll
        for (int mi = 0; mi < 2; mi++)
#pragma unroll
            for (int r = 0; r < 4; r++) {
                u32 w0 = IV[mi][r].x, w1 = IV[mi][r].y;
                accG[mi][0][r] += lo2f(w0);
                accG[mi][1][r] += hi2f(w0);
                accG[mi][2][r] += lo2f(w1);
                accG[mi][3][r] += hi2f(w1);
            }

        // ---- publish c2c ----
#pragma unroll
        for (int i = 0; i < 2; i++) {
            *(u32*)(ccB + ccP[2 * i]) = pack2(accC[i][0], accC[i][1]);
            *(u32*)(ccB + ccP[2 * i + 1]) = pack2(accC[i][2], accC[i][3]);
        }
        __syncthreads();

        // ---- stage B: LSTM update ----
#pragma unroll
        for (int mi = 0; mi < 2; mi++) {
            int p2 = p2s[mi];
            bool vst = (u32)(t - p2) < 64u;
            u16* hp = hp16[mi];
#pragma unroll
            for (int nb = 0; nb < 4; nb++) {
                u32 cw = *(const u32*)(ccB + ccR[mi][nb]);
                float cc = ((nq & 1) ? hi2f(cw) : lo2f(cw)) + bcc[nb];
                float si = sigm2(accG[mi][nb][0]);
                float sg = sigm2(accG[mi][nb][1]);
                float sf = sigm2(accG[mi][nb][2]);
                float so = sigm2(accG[mi][nb][3]);
                float c1 = __builtin_fmaf(sf, cc, si * sg);
                float h1 = so * tanh_fast(c1);
                u16 hb = f2bf(h1);
                *(u16*)(smB + wOff[mi][nb]) = hb;
                *(u16*)(smB + wOff[mi][nb] + 16384) = f2bf(c1);
                if (vst) hp[nb * 16] = hb;
            }
            hp16[mi] += 64;
        }
        __syncthreads();

        // ---- toggle parity ----
#pragma unroll
        for (int mi = 0; mi < 2; mi++) {
#pragma unroll
            for (int kt = 0; kt < 4; kt++) aG[mi][kt] ^= 8192;
#pragma unroll
            for (int nb = 0; nb < 4; nb++) wOff[mi][nb] ^= 8192;
        }
#pragma unroll
        for (int kt = 0; kt < 4; kt++) aC[kt] ^= 8192;
    }
}

// ---------------- K3: up-projection via MFMA ----------------
// per (b,r) block, 256 thr = 4 waves, wave = w-tile. A=w_upB, B=hh bf16.
__global__ __launch_bounds__(256) void up_kernel(
    const u16* __restrict__ hh16, const u16* __restrict__ w_upB,
    const float* __restrict__ b_up, float* __restrict__ out) {
    const int bid = blockIdx.x;
    const int b = bid >> 6, r = bid & 63;
    const int lane = threadIdx.x & 63;
    const int wt = __builtin_amdgcn_readfirstlane(threadIdx.x >> 6);
    const int m15 = lane & 15, g4 = lane >> 4;

    const u16* hh_b = hh16 + (size_t)b * 262144;
    const int w = 16 * wt + m15;

    bf16x8 Bf[2];
#pragma unroll
    for (int kt = 0; kt < 2; kt++)
        Bf[kt] = __builtin_bit_cast(
            bf16x8,
            *(const uint4*)(hh_b + (r * 4096 + w * 64 + kt * 32 + g4 * 8)));

    f32x4 acc[8] = {};
#pragma unroll
    for (int nt = 0; nt < 8; nt++) {
#pragma unroll
        for (int kt = 0; kt < 2; kt++) {
            bf16x8 Af = __builtin_bit_cast(
                bf16x8, *(const uint4*)(w_upB + ((16 * nt + m15) * 64 +
                                                 kt * 32 + g4 * 8)));
            acc[nt] = MFMA(Af, Bf[kt], acc[nt]);
        }
    }
    float* outb = out + (size_t)b * 524288;
#pragma unroll
    for (int nt = 0; nt < 8; nt++) {
#pragma unroll
        for (int rr = 0; rr < 4; rr++) {
            int o2 = 16 * nt + 4 * g4 + rr;
            outb[(size_t)o2 * 4096 + r * 64 + w] = acc[nt][rr] + b_up[o2];
        }
    }
}

extern "C" void kernel_launch(void* const* d_in, const int* in_sizes, int n_in,
                              void* d_out, int out_size, void* d_ws,
                              size_t ws_size, hipStream_t stream) {
    (void)in_sizes; (void)n_in; (void)out_size; (void)ws_size;
    const float* inputs = (const float*)d_in[0];
    const float* w_i2s = (const float*)d_in[1];
    const float* b_i2s = (const float*)d_in[2];
    const float* w_s2s = (const float*)d_in[3];
    const float* b_s2s = (const float*)d_in[4];
    const float* w_c2c = (const float*)d_in[5];
    const float* b_c2c = (const float*)d_in[6];
    const float* w_up = (const float*)d_in[7];
    const float* b_up = (const float*)d_in[8];
    float* out = (float*)d_out;
    char* ws = (char*)d_ws;

    // workspace layout (bytes):
    // [0, 69206016)             i2sP u16 (32*64*66*256, bias-padded slots)
    // [69206016, 85983232)      hh16 u16 (32*64*64*64)
    // [85983232, 86114304)      Wg fp32 (256*128, scaled -log2e)
    // [86114304, 86147072)      Wc fp32 (64*128)
    // [86147072, 86147584)      biasRow u16[256]
    // [86147584, 86163968)      w_upB u16 (128*64)
    u16* i2sP = (u16*)ws;
    u16* hh16 = (u16*)(ws + 69206016);
    float* Wg = (float*)(ws + 85983232);
    float* Wc = (float*)(ws + 86114304);
    u16* biasRow = (u16*)(ws + 86147072);
    u16* w_upB = (u16*)(ws + 86147584);

    hipLaunchKernelGGL(repack_w, dim3(193), dim3(256), 0, stream, w_s2s, w_c2c,
                       b_i2s, b_s2s, w_up, Wg, Wc, biasRow, w_upB);
    hipLaunchKernelGGL(i2s_kernel, dim3(2048), dim3(256), 0, stream, inputs,
                       w_i2s, b_i2s, b_s2s, (const u32*)biasRow, (u32*)i2sP);
    hipLaunchKernelGGL(scan_kernel, dim3(32), dim3(512), 0, stream, i2sP, Wg,
                       Wc, b_c2c, hh16);
    hipLaunchKernelGGL(up_kernel, dim3(2048), dim3(256), 0, stream, hh16,
                       w_upB, b_up, out);
}